// Round 8
// baseline (264.085 us; speedup 1.0000x reference)
//
#include <hip/hip_runtime.h>
#include <hip/hip_bf16.h>
#include <stdint.h>

// Problem constants (B=2, S=2048, D=1024, H=16, hd=64)
#define DIMD 1024
#define SEQ  2048
#define NH   16
#define MROWS 4096   // B*S
#define NQ   65536   // total q rows across (b,h)

typedef __bf16 bf16_t;
typedef bf16_t bf16x8 __attribute__((ext_vector_type(8)));
typedef float  f32x4  __attribute__((ext_vector_type(4)));
typedef unsigned short u16;
typedef unsigned short u16x4 __attribute__((ext_vector_type(4)));
typedef unsigned short u16x8 __attribute__((ext_vector_type(8)));
typedef unsigned int   u32;
typedef u32 u32x2 __attribute__((ext_vector_type(2)));

static __device__ __forceinline__ f32x4 mfma16(bf16x8 a, bf16x8 b, f32x4 c) {
    return __builtin_amdgcn_mfma_f32_16x16x32_bf16(a, b, c, 0, 0, 0);
}

static __device__ __forceinline__ float fast_exp2(float x) {
#if __has_builtin(__builtin_amdgcn_exp2f)
    return __builtin_amdgcn_exp2f(x);
#else
    return exp2f(x);
#endif
}

// async global->LDS 16B per lane; lds dest must be wave-uniform base + lane*16
#define GLD16(gsrc, ldst) __builtin_amdgcn_global_load_lds(                    \
    (const __attribute__((address_space(1))) unsigned int*)(gsrc),             \
    (__attribute__((address_space(3))) unsigned int*)(ldst), 16, 0, 0)

// Split fp32 into hi/lo bf16 by truncation: x ~= hi + lo, rel err <= 2^-16
static __device__ __forceinline__ void split_bf16(float x, u16& h, u16& l) {
    u32 u = __float_as_uint(x);
    u16 hu = (u16)(u >> 16);
    float xh = __uint_as_float((u32)hu << 16);
    float lo = x - xh;
    h = hu;
    l = (u16)(__float_as_uint(lo) >> 16);
}

static __device__ __forceinline__ u32 pack_bf16(float a, float b) {
    return (__float_as_uint(a) >> 16) | (__float_as_uint(b) & 0xffff0000u);
}
static __device__ __forceinline__ u32 pack_bf16_rn(float a, float b) {
    u32 ua = __float_as_uint(a) + 0x8000u;
    u32 ub = __float_as_uint(b) + 0x8000u;
    return (ua >> 16) | (ub & 0xffff0000u);
}
static __device__ __forceinline__ float bf_to_f(u16 v) {
    return __uint_as_float((u32)v << 16);
}

// ---------------------------------------------------------------------------
// Kernel 1: W[1024][1024] f32 -> W^T split hi/lo bf16, chunk-major tile layout
// for global_load_lds: region(nt,kt)=(nt*32+kt)*4096; within: cc*1024+r*8+e.
// Grid (kt 32, nt 8, z 3), 256 thr.
// ---------------------------------------------------------------------------
__global__ __launch_bounds__(256) void transWs3(
    const float* __restrict__ w0, const float* __restrict__ w1, const float* __restrict__ w2,
    u16* __restrict__ WTsH, u16* __restrict__ WTsL) {
    const int z = blockIdx.z;
    const float* W = z == 0 ? w0 : z == 1 ? w1 : w2;
    __shared__ u16 Hs[4096], Ls[4096];
    const int tid = threadIdx.x;
    const int kt = blockIdx.x, nt = blockIdx.y;
    const int n0 = nt * 128, k0 = kt * 32;
    #pragma unroll
    for (int i = 0; i < 4; i++) {
        int f = i * 256 + tid;
        int kr = f >> 5, nc4 = (f & 31) * 4;
        f32x4 w = *(const f32x4*)&W[(size_t)(k0 + kr) * DIMD + n0 + nc4];
        int cc = kr >> 3, e = kr & 7;
        #pragma unroll
        for (int j = 0; j < 4; j++) {
            u16 hh, ll; split_bf16(w[j], hh, ll);
            Hs[cc * 1024 + (nc4 + j) * 8 + e] = hh;
            Ls[cc * 1024 + (nc4 + j) * 8 + e] = ll;
        }
    }
    __syncthreads();
    const size_t base = (size_t)z * (DIMD * DIMD) + (size_t)(nt * 32 + kt) * 4096;
    #pragma unroll
    for (int i = 0; i < 2; i++) {
        int idx = (i * 256 + tid) * 8;
        *(u16x8*)(WTsH + base + idx) = *(const u16x8*)&Hs[idx];
        *(u16x8*)(WTsL + base + idx) = *(const u16x8*)&Ls[idx];
    }
}

// ---------------------------------------------------------------------------
// Kernel 2: 3 projection GEMMs (z = q/k/v). P = X @ W, split-bf16 (3 MFMA).
// proj7: B double-buffered LDS (GLD16 issued before MFMA phase), A register
// prefetch with XOR-swizzled 16B ds_writes. LDS 48KB -> 3 blocks/CU.
// Grid (x = m-tile 32, y = n-tile 8, z = 3) = 768 blocks = exactly 1 round.
// ---------------------------------------------------------------------------
__global__ __launch_bounds__(256, 3) void proj7(
    const float* __restrict__ xq, const float* __restrict__ xk, const float* __restrict__ xv,
    const u16* __restrict__ WTsH, const u16* __restrict__ WTsL,
    u16* __restrict__ qh, u16* __restrict__ ql,
    u16* __restrict__ kh, u16* __restrict__ kl,
    u16* __restrict__ vh) {

    const int z = blockIdx.z;
    const float* X = z == 0 ? xq : z == 1 ? xk : xv;
    const u16* BH = WTsH + (size_t)z * (DIMD * DIMD);
    const u16* BL = WTsL + (size_t)z * (DIMD * DIMD);
    u16* outH = z == 0 ? qh : z == 1 ? kh : vh;
    u16* outL = z == 0 ? ql : kl;               // unused when z==2 (guarded)
    const float oscale = z == 0 ? 0.0450842200278f : 1.0f;  // (1/32)*log2(e)

    // AsH | AsL | BsH0 | BsL0 | BsH1 | BsL1  (u16 units, 4096 each) = 48KB
    __shared__ u16 lds[24576];
    u16* AsH = lds;
    u16* AsL = lds + 4096;

    const int tid  = threadIdx.x;
    const int lane = tid & 63, wave = tid >> 6;
    const int quad = lane >> 4, l16 = lane & 15;
    const int wy = wave >> 1, wx = wave & 1;
    const int m0 = blockIdx.x * 128;            // row tile (A)
    const int n0 = blockIdx.y * 128;            // col tile (B)
    const size_t Bregion0 = (size_t)(blockIdx.y * 32) * 4096;

    // A staging geometry: thread covers (rA, ccA) and (rA+64, ccA);
    // 8 contiguous k-floats per pair -> one u16x8 store per array.
    const int rA  = tid >> 2, ccA = tid & 3;
    const int idxA0 = ccA * 1024 + ((rA ^ (ccA << 1)) * 8);   // XOR swizzle
    const int idxA1 = idxA0 + 512;                            // rA+64: bit6 unaffected
    const float* Xb0 = X + (size_t)(m0 + rA) * DIMD + ccA * 8;
    const float* Xb1 = X + (size_t)(m0 + rA + 64) * DIMD + ccA * 8;

    f32x4 acc[4][4];
    #pragma unroll
    for (int mt = 0; mt < 4; mt++)
        #pragma unroll
        for (int nt = 0; nt < 4; nt++) acc[mt][nt] = (f32x4)0.0f;

    f32x4 pa0, pa1, pa2, pa3;   // A prefetch registers (16 f32)

#define LOADA(kt) do {                                                         \
        pa0 = *(const f32x4*)(Xb0 + (kt) * 32);                                \
        pa1 = *(const f32x4*)(Xb0 + (kt) * 32 + 4);                            \
        pa2 = *(const f32x4*)(Xb1 + (kt) * 32);                                \
        pa3 = *(const f32x4*)(Xb1 + (kt) * 32 + 4);                            \
    } while (0)

#define WRITEA() do {                                                          \
        u16x8 h, l;                                                            \
        _Pragma("unroll")                                                      \
        for (int j = 0; j < 4; j++) {                                          \
            u16 hh, ll;                                                        \
            split_bf16(pa0[j], hh, ll); h[j] = hh;     l[j] = ll;              \
            split_bf16(pa1[j], hh, ll); h[4 + j] = hh; l[4 + j] = ll;          \
        }                                                                      \
        *(u16x8*)&AsH[idxA0] = h;                                              \
        *(u16x8*)&AsL[idxA0] = l;                                              \
        _Pragma("unroll")                                                      \
        for (int j = 0; j < 4; j++) {                                          \
            u16 hh, ll;                                                        \
            split_bf16(pa2[j], hh, ll); h[j] = hh;     l[j] = ll;              \
            split_bf16(pa3[j], hh, ll); h[4 + j] = hh; l[4 + j] = ll;          \
        }                                                                      \
        *(u16x8*)&AsH[idxA1] = h;                                              \
        *(u16x8*)&AsL[idxA1] = l;                                              \
    } while (0)

#define STAGEB(kt, buf) do {                                                   \
        const size_t rb = Bregion0 + (size_t)(kt) * 4096;                      \
        u16* BsHd = lds + 8192 + (buf) * 8192;                                 \
        u16* BsLd = BsHd + 4096;                                               \
        int c0 = tid, c1 = 256 + tid;                                          \
        GLD16(BH + rb + c0 * 8, &BsHd[c0 * 8]);                                \
        GLD16(BH + rb + c1 * 8, &BsHd[c1 * 8]);                                \
        GLD16(BL + rb + c0 * 8, &BsLd[c0 * 8]);                                \
        GLD16(BL + rb + c1 * 8, &BsLd[c1 * 8]);                                \
    } while (0)

    // prologue: stage tile 0 (A regs -> split/write; B -> GLD16 buf0)
    LOADA(0);
    STAGEB(0, 0);
    WRITEA();
    __syncthreads();                 // drains vmcnt (GLD16) + lgkm (A writes)

    for (int kt = 0; kt < 32; kt++) {
        const int cur = kt & 1;
        if (kt < 31) {               // issue next-tile loads: fly under MFMA
            LOADA(kt + 1);           // A loads first (oldest in vmcnt queue)
            STAGEB(kt + 1, cur ^ 1);
        }

        const u16* BsH = lds + 8192 + cur * 8192;
        const u16* BsL = BsH + 4096;

        bf16x8 aH[4], aL[4], bH[4], bL[4];
        #pragma unroll
        for (int mt = 0; mt < 4; mt++) {
            int r = wy * 64 + mt * 16 + l16;
            int idx = quad * 1024 + ((r ^ (quad << 1)) * 8);   // matching XOR
            aH[mt] = *(const bf16x8*)&AsH[idx];
            aL[mt] = *(const bf16x8*)&AsL[idx];
        }
        #pragma unroll
        for (int nt = 0; nt < 4; nt++) {
            int r = wx * 64 + nt * 16 + l16;
            bH[nt] = *(const bf16x8*)&BsH[(quad * 128 + r) * 8];
            bL[nt] = *(const bf16x8*)&BsL[(quad * 128 + r) * 8];
        }
        #pragma unroll
        for (int mt = 0; mt < 4; mt++)
            #pragma unroll
            for (int nt = 0; nt < 4; nt++) {
                acc[mt][nt] = mfma16(aH[mt], bH[nt], acc[mt][nt]);
                acc[mt][nt] = mfma16(aH[mt], bL[nt], acc[mt][nt]);
                acc[mt][nt] = mfma16(aL[mt], bH[nt], acc[mt][nt]);
            }

        __syncthreads();             // all waves done reading As (+vmcnt drain)
        if (kt < 31) WRITEA();       // split prefetched A, store for tile t+1
        __syncthreads();             // As(t+1) visible
    }
#undef LOADA
#undef WRITEA
#undef STAGEB

    #pragma unroll
    for (int mt = 0; mt < 4; mt++)
        #pragma unroll
        for (int nt = 0; nt < 4; nt++)
            #pragma unroll
            for (int r = 0; r < 4; r++) {
                int row = m0 + wy * 64 + mt * 16 + quad * 4 + r;
                int col = n0 + wx * 64 + nt * 16 + l16;
                u16 hh, ll; split_bf16(acc[mt][nt][r] * oscale, hh, ll);
                outH[(size_t)row * DIMD + col] = hh;
                if (z != 2) outL[(size_t)row * DIMD + col] = ll;
            }
}

// ---------------------------------------------------------------------------
// Kernel 3: flash attention, S^T formulation. flash13 = flash8 retried with
// the spill fixed: __launch_bounds__(512,2) -> VGPR cap 128 (kernel needs
// ~84; flash8's (512,4) capped at 64 -> 66MB scratch writeback, the whole
// regression). 8-wave blocks, Q-tile 256, KV-split 2. LDS = K/KL/V 27KB +
// Ps[8][32][72] 36KB = 63KB -> 2 blocks/CU = 16 waves/CU (vs flash12's 8).
// Grid (bh 32, qt 8, z 2) = 512 = exactly one round of 2/CU, no tail.
// Carries flash12's fused V-transpose staging (b16 scatter, XOR swizzle)
// and T13 defer-max. Writes bf16 unnormalized O + M,L; combineK merges.
// ---------------------------------------------------------------------------
__global__ __launch_bounds__(512, 2) void flash13(
    const u16* __restrict__ qh, const u16* __restrict__ ql,
    const u16* __restrict__ kh, const u16* __restrict__ kl,
    const u16* __restrict__ vh,
    u16* __restrict__ Opart, float* __restrict__ Mpart, float* __restrict__ Lpart) {

    __shared__ u16 KH[64][72], KL[64][72], VTs[64][72];
    __shared__ u16 Ps[8][32][72];

    const int tid  = threadIdx.x;
    const int lane = tid & 63, wv = tid >> 6;      // wv 0..7
    const int quad = lane >> 4, l16 = lane & 15;
    const int bh = blockIdx.x, z = blockIdx.z;
    const size_t slab = (size_t)bh * (SEQ * 64);
    const int q0 = blockIdx.y * 256 + wv * 32;
    const int jbase = z * 1024;

    bf16x8 qfH[2][2], qfL[2][2];
    #pragma unroll
    for (int mq = 0; mq < 2; mq++) {
        const size_t rb = slab + (size_t)(q0 + mq * 16 + l16) * 64;
        #pragma unroll
        for (int kk = 0; kk < 2; kk++) {
            qfH[mq][kk] = *(const bf16x8*)(qh + rb + kk * 32 + quad * 8);
            qfL[mq][kk] = *(const bf16x8*)(ql + rb + kk * 32 + quad * 8);
        }
    }

    f32x4 O[2][4];
    float M[2] = {-3.0e38f, -3.0e38f}, L[2] = {0.0f, 0.0f};
    #pragma unroll
    for (int mq = 0; mq < 2; mq++)
        #pragma unroll
        for (int nv = 0; nv < 4; nv++) O[mq][nv] = (f32x4)0.0f;

    // staging: 512 threads cover the 64x64 u16 tile with one b128 per array
    const int r0 = tid >> 3, c0 = (tid & 7) * 8;
    // V transpose-staging: vh[sq=r0][d=c0+j] -> VTs[c0+j][r0 ^ vswz]
    const int vswz  = ((c0 >> 3) & 7) << 3;
    const int vcol0 = r0 ^ vswz;
    u16x8 s0, s2, s4;

#define STAGEV() do {                                                          \
        _Pragma("unroll")                                                      \
        for (int j = 0; j < 8; j++) VTs[c0 + j][vcol0] = (u16)s4[j];           \
    } while (0)

    {   // preload tile 0 (V reads same coalesced [row][col] expr as K)
        const int j0 = jbase;
        s0 = *(const u16x8*)(kh + slab + (size_t)(j0 + r0) * 64 + c0);
        s2 = *(const u16x8*)(kl + slab + (size_t)(j0 + r0) * 64 + c0);
        s4 = *(const u16x8*)(vh + slab + (size_t)(j0 + r0) * 64 + c0);
    }
    *(u16x8*)&KH[r0][c0] = s0;
    *(u16x8*)&KL[r0][c0] = s2;
    STAGEV();
    __syncthreads();

    for (int t = 0; t < 16; t++) {
        if (t < 15) {   // prefetch next tile into registers
            const int j0 = jbase + (t + 1) * 64;
            s0 = *(const u16x8*)(kh + slab + (size_t)(j0 + r0) * 64 + c0);
            s2 = *(const u16x8*)(kl + slab + (size_t)(j0 + r0) * 64 + c0);
            s4 = *(const u16x8*)(vh + slab + (size_t)(j0 + r0) * 64 + c0);
        }

        // S^T = K·Q^T (split: Kh·Qh + Kl·Qh + Kh·Ql)
        f32x4 St[2][4];
        #pragma unroll
        for (int mq = 0; mq < 2; mq++)
            #pragma unroll
            for (int nt = 0; nt < 4; nt++) St[mq][nt] = (f32x4)0.0f;
        __builtin_amdgcn_s_setprio(1);
        #pragma unroll
        for (int nt = 0; nt < 4; nt++) {
            const int rB = nt * 16 + l16;
            #pragma unroll
            for (int kk = 0; kk < 2; kk++) {
                bf16x8 kHf = *(const bf16x8*)&KH[rB][kk * 32 + quad * 8];
                bf16x8 kLf = *(const bf16x8*)&KL[rB][kk * 32 + quad * 8];
                #pragma unroll
                for (int mq = 0; mq < 2; mq++) {
                    St[mq][nt] = mfma16(kHf, qfH[mq][kk], St[mq][nt]);
                    St[mq][nt] = mfma16(kLf, qfH[mq][kk], St[mq][nt]);
                    St[mq][nt] = mfma16(kHf, qfL[mq][kk], St[mq][nt]);
                }
            }
        }
        __builtin_amdgcn_s_setprio(0);

        // online softmax with defer-max (T13, THR=8 log2-units)
        #pragma unroll
        for (int mq = 0; mq < 2; mq++) {
            float mx = St[mq][0][0];
            #pragma unroll
            for (int nt = 0; nt < 4; nt++)
                #pragma unroll
                for (int r = 0; r < 4; r++) mx = fmaxf(mx, St[mq][nt][r]);
            mx = fmaxf(mx, __shfl_xor(mx, 16));
            mx = fmaxf(mx, __shfl_xor(mx, 32));
            float Mn = M[mq];
            if (__any(mx > Mn + 8.0f)) {
                Mn = fmaxf(Mn, mx);
                float al = fast_exp2(M[mq] - Mn);
                M[mq] = Mn;
                L[mq] *= al;
                #pragma unroll
                for (int nv = 0; nv < 4; nv++) O[mq][nv] *= al;
            }
            float rs = 0.0f;
            #pragma unroll
            for (int nt = 0; nt < 4; nt++)
                #pragma unroll
                for (int r = 0; r < 4; r++) {
                    float p = fast_exp2(St[mq][nt][r] - Mn);
                    St[mq][nt][r] = p;
                    rs += p;
                }
            rs += __shfl_xor(rs, 16);
            rs += __shfl_xor(rs, 32);
            L[mq] += rs;
            #pragma unroll
            for (int nt = 0; nt < 4; nt++) {
                u32x2 d;
                d[0] = pack_bf16(St[mq][nt][0], St[mq][nt][1]);
                d[1] = pack_bf16(St[mq][nt][2], St[mq][nt][3]);
                *(u32x2*)&Ps[wv][mq * 16 + l16][nt * 16 + quad * 4] = d;
            }
        }

        // O^T += V^T · P^T (wave-local P; intra-wave ordering via lgkmcnt)
        __builtin_amdgcn_s_setprio(1);
        #pragma unroll
        for (int kk = 0; kk < 2; kk++) {
            bf16x8 pB[2];
            #pragma unroll
            for (int mq = 0; mq < 2; mq++)
                pB[mq] = *(const bf16x8*)&Ps[wv][mq * 16 + l16][kk * 32 + quad * 8];
            #pragma unroll
            for (int nv = 0; nv < 4; nv++) {
                const int rowd = nv * 16 + l16;
                const int colr = (kk * 32 + quad * 8) ^ (((rowd >> 3) & 7) << 3);
                bf16x8 vF = *(const bf16x8*)&VTs[rowd][colr];
                #pragma unroll
                for (int mq = 0; mq < 2; mq++)
                    O[mq][nv] = mfma16(vF, pB[mq], O[mq][nv]);
            }
        }
        __builtin_amdgcn_s_setprio(0);

        __syncthreads();                 // all waves done reading tile t
        if (t < 15) {
            *(u16x8*)&KH[r0][c0] = s0;
            *(u16x8*)&KL[r0][c0] = s2;
            STAGEV();
        }
        __syncthreads();                 // tile t+1 visible
    }
#undef STAGEV

    // epilogue: bf16 unnormalized O + M, L for this half
    const int qgb = bh * SEQ + q0;
    #pragma unroll
    for (int mq = 0; mq < 2; mq++) {
        const int qg = qgb + mq * 16 + l16;
        #pragma unroll
        for (int nv = 0; nv < 4; nv++) {
            u32x2 d;
            d[0] = pack_bf16_rn(O[mq][nv][0], O[mq][nv][1]);
            d[1] = pack_bf16_rn(O[mq][nv][2], O[mq][nv][3]);
            *(u32x2*)(Opart + ((size_t)(z * NQ + qg)) * 64 + nv * 16 + quad * 4) = d;
        }
        if (quad == 0) {
            Mpart[z * NQ + qg] = M[mq];
            Lpart[z * NQ + qg] = L[mq];
        }
    }
}

// ---------------------------------------------------------------------------
// Kernel 4: combine the 2 KV-split halves -> final out [B,S,D]
// ---------------------------------------------------------------------------
__global__ __launch_bounds__(256) void combineK(
    const u16* __restrict__ Opart, const float* __restrict__ Mpart,
    const float* __restrict__ Lpart, float* __restrict__ out) {
    int idx = blockIdx.x * 256 + threadIdx.x;       // NQ*16 threads
    int qg = idx >> 4, c4 = (idx & 15) * 4;
    float M0 = Mpart[qg], M1 = Mpart[NQ + qg];
    float L0 = Lpart[qg], L1 = Lpart[NQ + qg];
    float Ms = fmaxf(M0, M1);
    float w0 = fast_exp2(M0 - Ms), w1 = fast_exp2(M1 - Ms);
    float inv = 1.0f / (w0 * L0 + w1 * L1);
    u16x4 a = *(const u16x4*)&Opart[(size_t)qg * 64 + c4];
    u16x4 b = *(const u16x4*)&Opart[((size_t)NQ + qg) * 64 + c4];
    f32x4 o;
    #pragma unroll
    for (int j = 0; j < 4; j++)
        o[j] = (w0 * bf_to_f(a[j]) + w1 * bf_to_f(b[j])) * inv;
    int bh = qg >> 11, s = qg & 2047;
    int bb = bh >> 4, h = bh & 15;
    *(f32x4*)&out[((size_t)(bb * SEQ + s)) * DIMD + h * 64 + c4] = o;
}

// ---------------------------------------------------------------------------
extern "C" void kernel_launch(void* const* d_in, const int* in_sizes, int n_in,
                              void* d_out, int out_size, void* d_ws, size_t ws_size,
                              hipStream_t stream) {
    const float* q  = (const float*)d_in[0];
    const float* k  = (const float*)d_in[1];
    const float* v  = (const float*)d_in[2];
    const float* wq = (const float*)d_in[3];
    const float* wk = (const float*)d_in[4];
    const float* wv = (const float*)d_in[5];
    float* out = (float*)d_out;

    char* ws = (char*)d_ws;
    const size_t MB = 1 << 20;
    u16* qh   = (u16*)(ws + 0 * MB);        // 8MB
    u16* ql   = (u16*)(ws + 8 * MB);        // 8MB
    u16* kh   = (u16*)(ws + 16 * MB);       // 8MB
    u16* kl   = (u16*)(ws + 24 * MB);       // 8MB
    u16* vh   = (u16*)(ws + 32 * MB);       // 8MB (live through flash13)
    u16* WTsH = (u16*)(ws + 40 * MB);       // 6MB (dead after proj7)
    u16* WTsL = (u16*)(ws + 46 * MB);       // 6MB (dead after proj7)
    u16* Opart = (u16*)(ws + 40 * MB);      // 16MB, overlays WTs
    float* Mpart = (float*)(ws + 56 * MB);  // 512KB
    float* Lpart = (float*)(ws + 56 * MB + 512 * 1024);  // peak ~57MB

    transWs3<<<dim3(32, 8, 3), 256, 0, stream>>>(wq, wk, wv, WTsH, WTsL);

    proj7<<<dim3(32, 8, 3), 256, 0, stream>>>(
        q, k, v, WTsH, WTsL, qh, ql, kh, kl, vh);

    flash13<<<dim3(2 * NH, SEQ / 256, 2), 512, 0, stream>>>(
        qh, ql, kh, kl, vh, Opart, Mpart, Lpart);

    combineK<<<dim3(NQ * 16 / 256), 256, 0, stream>>>(Opart, Mpart, Lpart, out);
}

// Round 9
// 244.027 us; speedup vs baseline: 1.0822x; 1.0822x over previous
//
#include <hip/hip_runtime.h>
#include <hip/hip_bf16.h>
#include <stdint.h>

// Problem constants (B=2, S=2048, D=1024, H=16, hd=64)
#define DIMD 1024
#define SEQ  2048
#define NH   16
#define MROWS 4096   // B*S
#define NQ   65536   // total q rows across (b,h)

typedef __bf16 bf16_t;
typedef bf16_t bf16x8 __attribute__((ext_vector_type(8)));
typedef float  f32x4  __attribute__((ext_vector_type(4)));
typedef unsigned short u16;
typedef unsigned short u16x4 __attribute__((ext_vector_type(4)));
typedef unsigned short u16x8 __attribute__((ext_vector_type(8)));
typedef unsigned int   u32;
typedef u32 u32x2 __attribute__((ext_vector_type(2)));

static __device__ __forceinline__ f32x4 mfma16(bf16x8 a, bf16x8 b, f32x4 c) {
    return __builtin_amdgcn_mfma_f32_16x16x32_bf16(a, b, c, 0, 0, 0);
}

static __device__ __forceinline__ float fast_exp2(float x) {
#if __has_builtin(__builtin_amdgcn_exp2f)
    return __builtin_amdgcn_exp2f(x);
#else
    return exp2f(x);
#endif
}

// async global->LDS 16B per lane; lds dest must be wave-uniform base + lane*16
#define GLD16(gsrc, ldst) __builtin_amdgcn_global_load_lds(                    \
    (const __attribute__((address_space(1))) unsigned int*)(gsrc),             \
    (__attribute__((address_space(3))) unsigned int*)(ldst), 16, 0, 0)

// Split fp32 into hi/lo bf16 by truncation: x ~= hi + lo, rel err <= 2^-16
static __device__ __forceinline__ void split_bf16(float x, u16& h, u16& l) {
    u32 u = __float_as_uint(x);
    u16 hu = (u16)(u >> 16);
    float xh = __uint_as_float((u32)hu << 16);
    float lo = x - xh;
    h = hu;
    l = (u16)(__float_as_uint(lo) >> 16);
}

static __device__ __forceinline__ u32 pack_bf16(float a, float b) {
    return (__float_as_uint(a) >> 16) | (__float_as_uint(b) & 0xffff0000u);
}

// ---------------------------------------------------------------------------
// Kernel 1: W[1024][1024] f32 -> W^T split hi/lo bf16, chunk-major tile layout
// for global_load_lds: region(nt,kt)=(nt*32+kt)*4096; within: cc*1024+r*8+e.
// Grid (kt 32, nt 8, z 3), 256 thr.
// ---------------------------------------------------------------------------
__global__ __launch_bounds__(256) void transWs3(
    const float* __restrict__ w0, const float* __restrict__ w1, const float* __restrict__ w2,
    u16* __restrict__ WTsH, u16* __restrict__ WTsL) {
    const int z = blockIdx.z;
    const float* W = z == 0 ? w0 : z == 1 ? w1 : w2;
    __shared__ u16 Hs[4096], Ls[4096];
    const int tid = threadIdx.x;
    const int kt = blockIdx.x, nt = blockIdx.y;
    const int n0 = nt * 128, k0 = kt * 32;
    #pragma unroll
    for (int i = 0; i < 4; i++) {
        int f = i * 256 + tid;
        int kr = f >> 5, nc4 = (f & 31) * 4;
        f32x4 w = *(const f32x4*)&W[(size_t)(k0 + kr) * DIMD + n0 + nc4];
        int cc = kr >> 3, e = kr & 7;
        #pragma unroll
        for (int j = 0; j < 4; j++) {
            u16 hh, ll; split_bf16(w[j], hh, ll);
            Hs[cc * 1024 + (nc4 + j) * 8 + e] = hh;
            Ls[cc * 1024 + (nc4 + j) * 8 + e] = ll;
        }
    }
    __syncthreads();
    const size_t base = (size_t)z * (DIMD * DIMD) + (size_t)(nt * 32 + kt) * 4096;
    #pragma unroll
    for (int i = 0; i < 2; i++) {
        int idx = (i * 256 + tid) * 8;
        *(u16x8*)(WTsH + base + idx) = *(const u16x8*)&Hs[idx];
        *(u16x8*)(WTsL + base + idx) = *(const u16x8*)&Ls[idx];
    }
}

// ---------------------------------------------------------------------------
// Kernel 2: 3 projection GEMMs (z = q/k/v). P = X @ W, split-bf16 (3 MFMA).
// proj7: B double-buffered LDS (GLD16 issued before MFMA phase), A register
// prefetch with XOR-swizzled 16B ds_writes. LDS 48KB -> 3 blocks/CU.
// Grid (x = m-tile 32, y = n-tile 8, z = 3) = 768 blocks = exactly 1 round.
// ---------------------------------------------------------------------------
__global__ __launch_bounds__(256, 3) void proj7(
    const float* __restrict__ xq, const float* __restrict__ xk, const float* __restrict__ xv,
    const u16* __restrict__ WTsH, const u16* __restrict__ WTsL,
    u16* __restrict__ qh, u16* __restrict__ ql,
    u16* __restrict__ kh, u16* __restrict__ kl,
    u16* __restrict__ vh) {

    const int z = blockIdx.z;
    const float* X = z == 0 ? xq : z == 1 ? xk : xv;
    const u16* BH = WTsH + (size_t)z * (DIMD * DIMD);
    const u16* BL = WTsL + (size_t)z * (DIMD * DIMD);
    u16* outH = z == 0 ? qh : z == 1 ? kh : vh;
    u16* outL = z == 0 ? ql : kl;               // unused when z==2 (guarded)
    const float oscale = z == 0 ? 0.0450842200278f : 1.0f;  // (1/32)*log2(e)

    // AsH | AsL | BsH0 | BsL0 | BsH1 | BsL1  (u16 units, 4096 each) = 48KB
    __shared__ u16 lds[24576];
    u16* AsH = lds;
    u16* AsL = lds + 4096;

    const int tid  = threadIdx.x;
    const int lane = tid & 63, wave = tid >> 6;
    const int quad = lane >> 4, l16 = lane & 15;
    const int wy = wave >> 1, wx = wave & 1;
    const int m0 = blockIdx.x * 128;            // row tile (A)
    const int n0 = blockIdx.y * 128;            // col tile (B)
    const size_t Bregion0 = (size_t)(blockIdx.y * 32) * 4096;

    // A staging geometry: thread covers (rA, ccA) and (rA+64, ccA);
    // 8 contiguous k-floats per pair -> one u16x8 store per array.
    const int rA  = tid >> 2, ccA = tid & 3;
    const int idxA0 = ccA * 1024 + ((rA ^ (ccA << 1)) * 8);   // XOR swizzle
    const int idxA1 = idxA0 + 512;                            // rA+64: bit6 unaffected
    const float* Xb0 = X + (size_t)(m0 + rA) * DIMD + ccA * 8;
    const float* Xb1 = X + (size_t)(m0 + rA + 64) * DIMD + ccA * 8;

    f32x4 acc[4][4];
    #pragma unroll
    for (int mt = 0; mt < 4; mt++)
        #pragma unroll
        for (int nt = 0; nt < 4; nt++) acc[mt][nt] = (f32x4)0.0f;

    f32x4 pa0, pa1, pa2, pa3;   // A prefetch registers (16 f32)

#define LOADA(kt) do {                                                         \
        pa0 = *(const f32x4*)(Xb0 + (kt) * 32);                                \
        pa1 = *(const f32x4*)(Xb0 + (kt) * 32 + 4);                            \
        pa2 = *(const f32x4*)(Xb1 + (kt) * 32);                                \
        pa3 = *(const f32x4*)(Xb1 + (kt) * 32 + 4);                            \
    } while (0)

#define WRITEA() do {                                                          \
        u16x8 h, l;                                                            \
        _Pragma("unroll")                                                      \
        for (int j = 0; j < 4; j++) {                                          \
            u16 hh, ll;                                                        \
            split_bf16(pa0[j], hh, ll); h[j] = hh;     l[j] = ll;              \
            split_bf16(pa1[j], hh, ll); h[4 + j] = hh; l[4 + j] = ll;          \
        }                                                                      \
        *(u16x8*)&AsH[idxA0] = h;                                              \
        *(u16x8*)&AsL[idxA0] = l;                                              \
        _Pragma("unroll")                                                      \
        for (int j = 0; j < 4; j++) {                                          \
            u16 hh, ll;                                                        \
            split_bf16(pa2[j], hh, ll); h[j] = hh;     l[j] = ll;              \
            split_bf16(pa3[j], hh, ll); h[4 + j] = hh; l[4 + j] = ll;          \
        }                                                                      \
        *(u16x8*)&AsH[idxA1] = h;                                              \
        *(u16x8*)&AsL[idxA1] = l;                                              \
    } while (0)

#define STAGEB(kt, buf) do {                                                   \
        const size_t rb = Bregion0 + (size_t)(kt) * 4096;                      \
        u16* BsHd = lds + 8192 + (buf) * 8192;                                 \
        u16* BsLd = BsHd + 4096;                                               \
        int c0 = tid, c1 = 256 + tid;                                          \
        GLD16(BH + rb + c0 * 8, &BsHd[c0 * 8]);                                \
        GLD16(BH + rb + c1 * 8, &BsHd[c1 * 8]);                                \
        GLD16(BL + rb + c0 * 8, &BsLd[c0 * 8]);                                \
        GLD16(BL + rb + c1 * 8, &BsLd[c1 * 8]);                                \
    } while (0)

    // prologue: stage tile 0 (A regs -> split/write; B -> GLD16 buf0)
    LOADA(0);
    STAGEB(0, 0);
    WRITEA();
    __syncthreads();                 // drains vmcnt (GLD16) + lgkm (A writes)

    for (int kt = 0; kt < 32; kt++) {
        const int cur = kt & 1;
        if (kt < 31) {               // issue next-tile loads: fly under MFMA
            LOADA(kt + 1);           // A loads first (oldest in vmcnt queue)
            STAGEB(kt + 1, cur ^ 1);
        }

        const u16* BsH = lds + 8192 + cur * 8192;
        const u16* BsL = BsH + 4096;

        bf16x8 aH[4], aL[4], bH[4], bL[4];
        #pragma unroll
        for (int mt = 0; mt < 4; mt++) {
            int r = wy * 64 + mt * 16 + l16;
            int idx = quad * 1024 + ((r ^ (quad << 1)) * 8);   // matching XOR
            aH[mt] = *(const bf16x8*)&AsH[idx];
            aL[mt] = *(const bf16x8*)&AsL[idx];
        }
        #pragma unroll
        for (int nt = 0; nt < 4; nt++) {
            int r = wx * 64 + nt * 16 + l16;
            bH[nt] = *(const bf16x8*)&BsH[(quad * 128 + r) * 8];
            bL[nt] = *(const bf16x8*)&BsL[(quad * 128 + r) * 8];
        }
        #pragma unroll
        for (int mt = 0; mt < 4; mt++)
            #pragma unroll
            for (int nt = 0; nt < 4; nt++) {
                acc[mt][nt] = mfma16(aH[mt], bH[nt], acc[mt][nt]);
                acc[mt][nt] = mfma16(aH[mt], bL[nt], acc[mt][nt]);
                acc[mt][nt] = mfma16(aL[mt], bH[nt], acc[mt][nt]);
            }

        __syncthreads();             // all waves done reading As (+vmcnt drain)
        if (kt < 31) WRITEA();       // split prefetched A, store for tile t+1
        __syncthreads();             // As(t+1) visible
    }
#undef LOADA
#undef WRITEA
#undef STAGEB

    #pragma unroll
    for (int mt = 0; mt < 4; mt++)
        #pragma unroll
        for (int nt = 0; nt < 4; nt++)
            #pragma unroll
            for (int r = 0; r < 4; r++) {
                int row = m0 + wy * 64 + mt * 16 + quad * 4 + r;
                int col = n0 + wx * 64 + nt * 16 + l16;
                u16 hh, ll; split_bf16(acc[mt][nt][r] * oscale, hh, ll);
                outH[(size_t)row * DIMD + col] = hh;
                if (z != 2) outL[(size_t)row * DIMD + col] = ll;
            }
}

// ---------------------------------------------------------------------------
// Kernel 3: flash attention, S^T formulation, KV-split 1. flash14 = flash12
// + V double-buffer (VT2, +9KB -> 55296B LDS, still 2 blocks/CU) enabling
// staging-under-PV: the K/V LDS writes for tile t+1 now execute in the same
// barrier window as PV(t) (V writes go to the alternate buffer; K reads of
// tile t all completed before bar1). Previously the staging block sat alone
// between the two barriers -- pure serial time each tile.
//   loop: QK(t) -> SM(t) -> bar1 -> {stage(t+1) || PV(t,cur)} -> bar2
// GLB(t+2) issued post-bar1 (a full tile of HBM latency hiding).
// launch_bounds (256,2): VGPR cap 128 (flash8 lesson: (x,4)->64 = spill).
// ---------------------------------------------------------------------------
__global__ __launch_bounds__(256, 2) void flash14(
    const u16* __restrict__ qh, const u16* __restrict__ ql,
    const u16* __restrict__ kh, const u16* __restrict__ kl,
    const u16* __restrict__ vh, float* __restrict__ out) {

    __shared__ u16 KH[64][72], KL[64][72];
    __shared__ u16 VT2[2][64][72];
    __shared__ u16 Ps[4][32][72];

    const int tid  = threadIdx.x;
    const int lane = tid & 63, wv = tid >> 6;
    const int quad = lane >> 4, l16 = lane & 15;
    const int bh = blockIdx.x;
    const size_t slab = (size_t)bh * (SEQ * 64);
    const int q0 = blockIdx.y * 128 + wv * 32;

    bf16x8 qfH[2][2], qfL[2][2];
    #pragma unroll
    for (int mq = 0; mq < 2; mq++) {
        const size_t rb = slab + (size_t)(q0 + mq * 16 + l16) * 64;
        #pragma unroll
        for (int kk = 0; kk < 2; kk++) {
            qfH[mq][kk] = *(const bf16x8*)(qh + rb + kk * 32 + quad * 8);
            qfL[mq][kk] = *(const bf16x8*)(ql + rb + kk * 32 + quad * 8);
        }
    }

    f32x4 O[2][4];
    float M[2] = {-3.0e38f, -3.0e38f}, L[2] = {0.0f, 0.0f};
    #pragma unroll
    for (int mq = 0; mq < 2; mq++)
        #pragma unroll
        for (int nv = 0; nv < 4; nv++) O[mq][nv] = (f32x4)0.0f;

    const int f0 = tid, f1 = 256 + tid;
    const int r0 = f0 >> 3, c0 = (f0 & 7) * 8;
    const int r1 = f1 >> 3, c1 = (f1 & 7) * 8;
    // V transpose-staging: vh[sq=r][d=c+j] -> VT2[vb][c+j][r ^ vswz]
    const int vswz  = ((c0 >> 3) & 7) << 3;
    const int vcol0 = r0 ^ vswz;
    const int vcol1 = r1 ^ vswz;
    u16x8 s0, s1, s2, s3, s4, s5;

#define GLB(j0t) do {                                                          \
        const int j0 = (j0t) * 64;                                             \
        s0 = *(const u16x8*)(kh + slab + (size_t)(j0 + r0) * 64 + c0);         \
        s1 = *(const u16x8*)(kh + slab + (size_t)(j0 + r1) * 64 + c1);         \
        s2 = *(const u16x8*)(kl + slab + (size_t)(j0 + r0) * 64 + c0);         \
        s3 = *(const u16x8*)(kl + slab + (size_t)(j0 + r1) * 64 + c1);         \
        s4 = *(const u16x8*)(vh + slab + (size_t)(j0 + r0) * 64 + c0);         \
        s5 = *(const u16x8*)(vh + slab + (size_t)(j0 + r1) * 64 + c1);         \
    } while (0)

#define STAGEKV(vb) do {                                                       \
        *(u16x8*)&KH[r0][c0] = s0;  *(u16x8*)&KH[r1][c1] = s1;                 \
        *(u16x8*)&KL[r0][c0] = s2;  *(u16x8*)&KL[r1][c1] = s3;                 \
        _Pragma("unroll")                                                      \
        for (int j = 0; j < 8; j++) {                                          \
            VT2[vb][c0 + j][vcol0] = (u16)s4[j];                               \
            VT2[vb][c1 + j][vcol1] = (u16)s5[j];                               \
        }                                                                      \
    } while (0)

    // prologue: tile 0 -> K + V buf0; regs <- tile 1
    GLB(0);
    STAGEKV(0);
    GLB(1);
    __syncthreads();

    int cur = 0;
    for (int t = 0; t < 32; t++) {
        // S^T = K·Q^T (split: Kh·Qh + Kl·Qh + Kh·Ql)
        f32x4 St[2][4];
        #pragma unroll
        for (int mq = 0; mq < 2; mq++)
            #pragma unroll
            for (int nt = 0; nt < 4; nt++) St[mq][nt] = (f32x4)0.0f;
        __builtin_amdgcn_s_setprio(1);
        #pragma unroll
        for (int nt = 0; nt < 4; nt++) {
            const int rB = nt * 16 + l16;
            #pragma unroll
            for (int kk = 0; kk < 2; kk++) {
                bf16x8 kHf = *(const bf16x8*)&KH[rB][kk * 32 + quad * 8];
                bf16x8 kLf = *(const bf16x8*)&KL[rB][kk * 32 + quad * 8];
                #pragma unroll
                for (int mq = 0; mq < 2; mq++) {
                    St[mq][nt] = mfma16(kHf, qfH[mq][kk], St[mq][nt]);
                    St[mq][nt] = mfma16(kLf, qfH[mq][kk], St[mq][nt]);
                    St[mq][nt] = mfma16(kHf, qfL[mq][kk], St[mq][nt]);
                }
            }
        }
        __builtin_amdgcn_s_setprio(0);

        // online softmax with defer-max (T13, THR=8 log2-units)
        #pragma unroll
        for (int mq = 0; mq < 2; mq++) {
            float mx = St[mq][0][0];
            #pragma unroll
            for (int nt = 0; nt < 4; nt++)
                #pragma unroll
                for (int r = 0; r < 4; r++) mx = fmaxf(mx, St[mq][nt][r]);
            mx = fmaxf(mx, __shfl_xor(mx, 16));
            mx = fmaxf(mx, __shfl_xor(mx, 32));
            float Mn = M[mq];
            if (__any(mx > Mn + 8.0f)) {
                Mn = fmaxf(Mn, mx);
                float al = fast_exp2(M[mq] - Mn);
                M[mq] = Mn;
                L[mq] *= al;
                #pragma unroll
                for (int nv = 0; nv < 4; nv++) O[mq][nv] *= al;
            }
            float rs = 0.0f;
            #pragma unroll
            for (int nt = 0; nt < 4; nt++)
                #pragma unroll
                for (int r = 0; r < 4; r++) {
                    float p = fast_exp2(St[mq][nt][r] - Mn);
                    St[mq][nt][r] = p;
                    rs += p;
                }
            rs += __shfl_xor(rs, 16);
            rs += __shfl_xor(rs, 32);
            L[mq] += rs;
            #pragma unroll
            for (int nt = 0; nt < 4; nt++) {
                u32x2 d;
                d[0] = pack_bf16(St[mq][nt][0], St[mq][nt][1]);
                d[1] = pack_bf16(St[mq][nt][2], St[mq][nt][3]);
                *(u32x2*)&Ps[wv][mq * 16 + l16][nt * 16 + quad * 4] = d;
            }
        }

        __syncthreads();                 // bar1: all waves done K-reads of t

        if (t < 31) {
            STAGEKV(cur ^ 1);            // K overwrite safe; V -> alt buffer
            if (t < 30) GLB(t + 2);      // issue next global loads early
        }

        // O^T += V^T · P^T from VT2[cur] (overlaps the staging above)
        __builtin_amdgcn_s_setprio(1);
        #pragma unroll
        for (int kk = 0; kk < 2; kk++) {
            bf16x8 pB[2];
            #pragma unroll
            for (int mq = 0; mq < 2; mq++)
                pB[mq] = *(const bf16x8*)&Ps[wv][mq * 16 + l16][kk * 32 + quad * 8];
            #pragma unroll
            for (int nv = 0; nv < 4; nv++) {
                const int rowd = nv * 16 + l16;
                const int colr = (kk * 32 + quad * 8) ^ (((rowd >> 3) & 7) << 3);
                bf16x8 vF = *(const bf16x8*)&VT2[cur][rowd][colr];
                #pragma unroll
                for (int mq = 0; mq < 2; mq++)
                    O[mq][nv] = mfma16(vF, pB[mq], O[mq][nv]);
            }
        }
        __builtin_amdgcn_s_setprio(0);

        __syncthreads();                 // bar2: staging of t+1 visible
        cur ^= 1;
    }
#undef GLB
#undef STAGEKV

    // epilogue: normalize and write final f32 out [B,S,D] directly.
    const int bb = bh >> 4, hh = bh & 15;
    #pragma unroll
    for (int mq = 0; mq < 2; mq++) {
        const int s = q0 + mq * 16 + l16;
        const float inv = 1.0f / L[mq];
        float* orow = out + ((size_t)(bb * SEQ + s)) * DIMD + hh * 64;
        #pragma unroll
        for (int nv = 0; nv < 4; nv++) {
            f32x4 o4;
            #pragma unroll
            for (int r = 0; r < 4; r++) o4[r] = O[mq][nv][r] * inv;
            *(f32x4*)(orow + nv * 16 + quad * 4) = o4;
        }
    }
}

// ---------------------------------------------------------------------------
extern "C" void kernel_launch(void* const* d_in, const int* in_sizes, int n_in,
                              void* d_out, int out_size, void* d_ws, size_t ws_size,
                              hipStream_t stream) {
    const float* q  = (const float*)d_in[0];
    const float* k  = (const float*)d_in[1];
    const float* v  = (const float*)d_in[2];
    const float* wq = (const float*)d_in[3];
    const float* wk = (const float*)d_in[4];
    const float* wv = (const float*)d_in[5];
    float* out = (float*)d_out;

    char* ws = (char*)d_ws;
    const size_t MB = 1 << 20;
    u16* qh   = (u16*)(ws + 0 * MB);        // 8MB
    u16* ql   = (u16*)(ws + 8 * MB);        // 8MB
    u16* kh   = (u16*)(ws + 16 * MB);       // 8MB
    u16* kl   = (u16*)(ws + 24 * MB);       // 8MB
    u16* vh   = (u16*)(ws + 32 * MB);       // 8MB (live through flash14)
    u16* WTsH = (u16*)(ws + 40 * MB);       // 6MB (dead after proj7)
    u16* WTsL = (u16*)(ws + 46 * MB);       // 6MB (dead after proj7); peak 52MB

    transWs3<<<dim3(32, 8, 3), 256, 0, stream>>>(wq, wk, wv, WTsH, WTsL);

    proj7<<<dim3(32, 8, 3), 256, 0, stream>>>(
        q, k, v, WTsH, WTsL, qh, ql, kh, kl, vh);

    flash14<<<dim3(2 * NH, SEQ / 128), 256, 0, stream>>>(
        qh, ql, kh, kl, vh, out);
}